// Round 3
// baseline (519.040 us; speedup 1.0000x reference)
//
#include <hip/hip_runtime.h>
#include <hip/hip_fp16.h>

// Rotation_9242769622431 — round 3: dtype-probing direct rotation kernel.
// Forensics: rounds 1-2 produced finite absmax ~1e20 from a pipeline whose
// every value is bounded (<1e3) under the assumed bf16 I/O — impossible unless
// the buffers are a WIDER type misread as bf16. The harness dtype list has no
// float16 entry; reference arrays are jnp.float16. So we probe the actual
// storage dtype on-device (channel_scales is strictly in [0.5,1.5] -> packed
// 16-bit buffers have ALL 16-bit halves in a narrow bit range; fp32 buffers
// have uniform-random low shorts), then run a direct LDS Givens-rotation
// kernel branching uniformly on the flag. MFMA path returns once dtype is pinned.

typedef unsigned int uint32;

#define DIM    4096
#define GROUP  128
#define KROT   8
#define NGROUP 32

__device__ __forceinline__ float bf16_to_f(unsigned short u) {
    union { uint32 i; float f; } v; v.i = ((uint32)u) << 16; return v.f;
}
__device__ __forceinline__ unsigned short f_to_bf16(float f) {
    union { float f; uint32 i; } v; v.f = f;
    uint32 x = v.i;
    return (unsigned short)((x + 0x7fffu + ((x >> 16) & 1u)) >> 16);  // RNE
}
__device__ __forceinline__ float fp16_to_f(unsigned short u) {
    __half h = __ushort_as_half(u); return __half2float(h);
}
__device__ __forceinline__ unsigned short f_to_fp16(float f) {
    return __half_as_ushort(__float2half_rn(f));
}

// flag: 0 = fp32, 1 = bf16, 2 = fp16
__global__ __launch_bounds__(256) void detect_dtype(const uint32* __restrict__ scw,
                                                    int* __restrict__ flag) {
    __shared__ int cbf[256], cfp16[256];
    int b = 0, h = 0;
    for (int i = threadIdx.x; i < 2048; i += 256) {   // 8 KB: in-bounds for all dtypes
        uint32 lo = scw[i] & 0xffffu;
        b += (lo >= 0x3F00u && lo <= 0x3FC0u);        // bf16 in [0.5, 1.5]
        h += (lo >= 0x3800u && lo <= 0x3E00u);        // fp16 in [0.5, 1.5]
    }
    cbf[threadIdx.x] = b; cfp16[threadIdx.x] = h;
    __syncthreads();
    for (int s = 128; s > 0; s >>= 1) {
        if (threadIdx.x < s) { cbf[threadIdx.x] += cbf[threadIdx.x + s];
                               cfp16[threadIdx.x] += cfp16[threadIdx.x + s]; }
        __syncthreads();
    }
    if (threadIdx.x == 0)
        *flag = (cbf[0] > 1024) ? 1 : ((cfp16[0] > 1024) ? 2 : 0);
}

// ---------------------------------------------------------------------------
// Direct rotation: block = (group g, 64-row tile). Stage tile in LDS fp32,
// apply 8 Givens layers (rows wave-private -> no inter-layer barriers),
// scale, store. Branches on dtype flag are grid-uniform.
// ---------------------------------------------------------------------------
__global__ __launch_bounds__(256) void rotate_direct(
    const void* __restrict__ Xv,
    const int*  __restrict__ pairs,
    const void* __restrict__ thetav,
    const void* __restrict__ scalesv,
    void* __restrict__ Outv,
    const int* __restrict__ flagp, int defflag)
{
    __shared__ float tile[64][GROUP + 2];
    __shared__ float scl[GROUP];
    const int g    = blockIdx.x;
    const int row0 = blockIdx.y * 64;
    const int tid  = threadIdx.x;
    const int dt   = flagp ? *flagp : defflag;

    // preload scales (before first barrier)
    if (tid < GROUP) {
        int c = g * GROUP + tid;
        scl[tid] = (dt == 1) ? bf16_to_f(((const unsigned short*)scalesv)[c])
                 : (dt == 2) ? fp16_to_f(((const unsigned short*)scalesv)[c])
                 : ((const float*)scalesv)[c];
    }

    // per-thread rotation params: pair p, wave-private rows [wr0, wr0+16)
    const int p   = tid & 63;
    const int wr0 = (tid >> 6) * 16;
    int Ak[KROT], Bk[KROT]; float ck[KROT], sk[KROT];
    #pragma unroll
    for (int k = 0; k < KROT; ++k) {
        Ak[k] = pairs[k * DIM + g * GROUP + 2 * p];       // local 0..127
        Bk[k] = pairs[k * DIM + g * GROUP + 2 * p + 1];
        int ti = k * (DIM / 2) + g * (GROUP / 2) + p;
        float th = (dt == 1) ? bf16_to_f(((const unsigned short*)thetav)[ti])
                 : (dt == 2) ? fp16_to_f(((const unsigned short*)thetav)[ti])
                 : ((const float*)thetav)[ti];
        ck[k] = __builtin_cosf(th);
        sk[k] = __builtin_sinf(th);
    }

    // ---- load tile ----
    if (dt == 0) {
        const float4* X4 = (const float4*)Xv;
        for (int i = tid; i < 64 * 32; i += 256) {
            int r = i >> 5, c4 = i & 31;
            float4 v = X4[(size_t)(row0 + r) * (DIM / 4) + g * (GROUP / 4) + c4];
            tile[r][c4 * 4 + 0] = v.x; tile[r][c4 * 4 + 1] = v.y;
            tile[r][c4 * 4 + 2] = v.z; tile[r][c4 * 4 + 3] = v.w;
        }
    } else {
        const uint4* X4 = (const uint4*)Xv;     // 8 halves per load
        for (int i = tid; i < 64 * 16; i += 256) {
            int r = i >> 4, c8 = i & 15;
            uint4 w = X4[(size_t)(row0 + r) * (DIM / 8) + g * (GROUP / 8) + c8];
            uint32 ws[4] = { w.x, w.y, w.z, w.w };
            #pragma unroll
            for (int h2 = 0; h2 < 4; ++h2) {
                unsigned short lo = (unsigned short)(ws[h2] & 0xffffu);
                unsigned short hi = (unsigned short)(ws[h2] >> 16);
                tile[r][c8 * 8 + 2 * h2]     = (dt == 1) ? bf16_to_f(lo) : fp16_to_f(lo);
                tile[r][c8 * 8 + 2 * h2 + 1] = (dt == 1) ? bf16_to_f(hi) : fp16_to_f(hi);
            }
        }
    }
    __syncthreads();

    // ---- 8 Givens layers. Rows wave-private; same-wave lanes hit disjoint
    // columns (pairs is a permutation) -> no barriers needed between layers.
    #pragma unroll
    for (int k = 0; k < KROT; ++k) {
        #pragma unroll
        for (int rr = 0; rr < 16; ++rr) {
            int r = wr0 + rr;
            float xa = tile[r][Ak[k]], xb = tile[r][Bk[k]];
            tile[r][Ak[k]] = ck[k] * xa - sk[k] * xb;
            tile[r][Bk[k]] = sk[k] * xa + ck[k] * xb;
        }
    }
    __syncthreads();

    // ---- scale + store ----
    if (dt == 0) {
        float4* O4 = (float4*)Outv;
        for (int i = tid; i < 64 * 32; i += 256) {
            int r = i >> 5, c4 = i & 31;
            float4 v;
            v.x = tile[r][c4 * 4 + 0] * scl[c4 * 4 + 0];
            v.y = tile[r][c4 * 4 + 1] * scl[c4 * 4 + 1];
            v.z = tile[r][c4 * 4 + 2] * scl[c4 * 4 + 2];
            v.w = tile[r][c4 * 4 + 3] * scl[c4 * 4 + 3];
            O4[(size_t)(row0 + r) * (DIM / 4) + g * (GROUP / 4) + c4] = v;
        }
    } else {
        uint4* O4 = (uint4*)Outv;
        for (int i = tid; i < 64 * 16; i += 256) {
            int r = i >> 4, c8 = i & 15;
            uint32 ws[4];
            #pragma unroll
            for (int h2 = 0; h2 < 4; ++h2) {
                float lo = tile[r][c8 * 8 + 2 * h2]     * scl[c8 * 8 + 2 * h2];
                float hi = tile[r][c8 * 8 + 2 * h2 + 1] * scl[c8 * 8 + 2 * h2 + 1];
                unsigned short ulo = (dt == 1) ? f_to_bf16(lo) : f_to_fp16(lo);
                unsigned short uhi = (dt == 1) ? f_to_bf16(hi) : f_to_fp16(hi);
                ws[h2] = (uint32)ulo | ((uint32)uhi << 16);
            }
            uint4 w; w.x = ws[0]; w.y = ws[1]; w.z = ws[2]; w.w = ws[3];
            O4[(size_t)(row0 + r) * (DIM / 8) + g * (GROUP / 8) + c8] = w;
        }
    }
}

extern "C" void kernel_launch(void* const* d_in, const int* in_sizes, int n_in,
                              void* d_out, int out_size, void* d_ws, size_t ws_size,
                              hipStream_t stream) {
    const void* x      = d_in[0];
    const int*  pairs  = (const int*)d_in[1];
    const void* theta  = d_in[2];
    const void* scales = d_in[3];

    const int N = in_sizes[0] / DIM;       // 16384
    const int nrowtiles = N / 64;          // 256

    int* flag = nullptr;
    if (d_ws != nullptr && ws_size >= sizeof(int)) {
        flag = (int*)d_ws;
        detect_dtype<<<1, 256, 0, stream>>>((const uint32*)scales, flag);
    }
    // default fp32 if no workspace for the flag (primary theory)
    rotate_direct<<<dim3(NGROUP, nrowtiles), 256, 0, stream>>>(
        x, pairs, theta, scales, d_out, flag, 0);
}